// Round 3
// baseline (1696.862 us; speedup 1.0000x reference)
//
#include <hip/hip_runtime.h>
#include <stdint.h>
#include <math.h>

// HierarchicalSoftmax: out[b, i*225+j] = softmax(x@W0+b0)[b,i] * softmax(x@W1+b1)[b,j], f<50257
//
// Pipeline:
//  1) hs_prep : W0,W1 fp32 [K][225] -> ws: per-K-tile images of W^T [480][BK] bf16 hi/lo,
//               XOR-swizzled so GEMM can global_load_lds linearly and ds_read conflict-free.
//  2) hs_gemm : logits = x @ [W0|W1] via 3-term bf16 split (hi*hi + lo*hi + hi*lo), fp32 acc,
//               split-K partials to ws. 2m x 4n waves (interleaved n-frags), counted-vmcnt
//               double-buffer: stage/write at iteration top, vmcnt(2) before barrier.
//  3) hs_finish: reduce partials + bias, per-head softmax, fused outer-product store.

#define BATCH   2048
#define KDIM    50257
#define LSZ     225
#define HOFF    240        // head1 column offset in padded logits
#define NPAD    480        // padded N: [0,225) = head0, [240,465) = head1, rest zero
#define BK      32
#define BM      128
#define NT      1571       // ceil(50257/32)
#define TILE_B  61440      // B tile bytes: 480 rows * 64B * 2 (hi+lo)
#define A_BYTES 16384      // A tile bytes: 128 rows * 64B * 2 (hi+lo)
#define BUF_B   77824      // TILE_B + A_BYTES
#define LDS_TOT 155648     // 2 * BUF_B (double buffer)

typedef __attribute__((ext_vector_type(8))) __bf16  bf16x8;
typedef __attribute__((ext_vector_type(4))) float   f32x4;

__device__ __forceinline__ unsigned short f2bf(float f) {   // RNE fp32->bf16
  unsigned int u = __float_as_uint(f);
  u += 0x7FFFu + ((u >> 16) & 1u);
  return (unsigned short)(u >> 16);
}
__device__ __forceinline__ float bf2f(unsigned short h) {
  return __uint_as_float(((unsigned int)h) << 16);
}
// XOR swizzle: flip byte-offset bits 4-5 by row bits 1-2 -> frag ds_read_b128 is 2-way (free)
__device__ __forceinline__ int swzr(int r) { return ((r >> 1) & 3) << 4; }

#define ASM_VMCNT0() asm volatile("s_waitcnt vmcnt(0)" ::: "memory")
#define ASM_VMCNT2() asm volatile("s_waitcnt vmcnt(2)" ::: "memory")
#define ASM_LGKM0()  asm volatile("s_waitcnt lgkmcnt(0)" ::: "memory")

// ---------------- prep: build swizzled, tiled bf16 hi/lo W^T ----------------
__global__ __launch_bounds__(512) void hs_prep(const float* __restrict__ W0,
                                               const float* __restrict__ W1,
                                               unsigned char* __restrict__ wt) {
  const int kt = blockIdx.x;           // one K-tile per block
  const int k0 = kt * BK;
  unsigned char* tb = wt + (size_t)kt * TILE_B;
  for (int idx = threadIdx.x; idx < NPAD * 8; idx += 512) {
    const int n = idx >> 3, c4 = idx & 7;       // row n, 4-elem group c4
    const float* src = nullptr;
    if (n < HOFF) { if (n < LSZ) src = W0 + n; }
    else          { if (n - HOFF < LSZ) src = W1 + (n - HOFF); }
    unsigned short he[4], le[4];
#pragma unroll
    for (int e = 0; e < 4; ++e) {
      const int k = k0 + c4 * 4 + e;
      float v = (src != nullptr && k < KDIM) ? src[(size_t)k * LSZ] : 0.0f;
      const unsigned short h = f2bf(v);
      he[e] = h;
      le[e] = f2bf(v - bf2f(h));
    }
    const int jp = (c4 * 8) ^ swzr(n);
    *(ushort4*)(tb + n * 64 + jp)         = make_ushort4(he[0], he[1], he[2], he[3]);
    *(ushort4*)(tb + 30720 + n * 64 + jp) = make_ushort4(le[0], le[1], le[2], le[3]);
  }
}

// ---------------- GEMM: 128x480 tile, BK=32, 8 waves (2m x 4n), split-K ----------------
__global__ __launch_bounds__(512, 2) void hs_gemm(
    const float* __restrict__ x, const unsigned char* __restrict__ wt,
    float* __restrict__ partials, int ksplit, int tpc) {
  extern __shared__ __align__(16) unsigned char smem[];
  const int bid   = blockIdx.x;
  const int chunk = bid % ksplit;            // same-chunk blocks share XCD (bid%8 == chunk%8)
  const int mtile = bid / ksplit;
  const int t0 = chunk * tpc;
  int t1 = t0 + tpc; if (t1 > NT) t1 = NT;
  const int m0 = mtile * BM;
  const int tid = threadIdx.x;
  const int lane = tid & 63, wid = tid >> 6;
  const int wm = wid >> 2, wn = wid & 3;     // wave tile: 64 rows x interleaved n-frags
  const int nfc = (wn < 2) ? 8 : 7;          // n-frags this wave owns (nf = wn + 4*i), total 30
  const int jl  = (lane >> 4) * 16;          // frag k-offset bytes
  const int l15 = lane & 15;

  // A staging geometry: thread covers rows arow0 and arow0+64, 4 k-elems each
  const int arow0 = tid >> 3, c4 = tid & 7;
  const int arow1 = arow0 + 64;
  const float* xr0 = x + (size_t)(m0 + arow0) * KDIM + c4 * 4;
  const float* xr1 = xr0 + (size_t)64 * KDIM;
  const int aoff0 = arow0 * 64 + ((c4 * 8) ^ swzr(arow0));
  const int aoff1 = arow1 * 64 + ((c4 * 8) ^ swzr(arow1));

  f32x4 acc[4][8];
#pragma unroll
  for (int mf = 0; mf < 4; ++mf)
#pragma unroll
    for (int i = 0; i < 8; ++i)
      acc[mf][i] = f32x4{0.f, 0.f, 0.f, 0.f};

  auto stageB = [&](int kt, int buf) {   // 60 x 1KB wave-chunks, pre-swizzled in ws
    const unsigned char* src = wt + (size_t)kt * TILE_B + lane * 16;
    unsigned char* dstb = smem + buf * BUF_B;
#pragma unroll
    for (int c = 0; c < 8; ++c) {
      const int cc = wid + c * 8;
      if (cc < 60) {
        __builtin_amdgcn_global_load_lds(
            (const __attribute__((address_space(1))) unsigned int*)(src + cc * 1024),
            (__attribute__((address_space(3))) unsigned int*)(dstb + cc * 1024),
            16, 0, 0);
      }
    }
  };

  auto loadA = [&](int kt, f32x4& v0, f32x4& v1) {
    const int kb = kt * BK + c4 * 4;
    const float* p0 = xr0 + (size_t)kt * BK;
    const float* p1 = xr1 + (size_t)kt * BK;
    if (kb + 4 <= KDIM) {
      __builtin_memcpy(&v0, p0, 16);
      __builtin_memcpy(&v1, p1, 16);
    } else {
#pragma unroll
      for (int e = 0; e < 4; ++e) {
        v0[e] = (kb + e < KDIM) ? p0[e] : 0.f;
        v1[e] = (kb + e < KDIM) ? p1[e] : 0.f;
      }
    }
  };

  auto writeA = [&](int buf, const f32x4& v0, const f32x4& v1) {
    unsigned char* ab = smem + buf * BUF_B + TILE_B;
    unsigned short h0e[4], l0e[4], h1e[4], l1e[4];
#pragma unroll
    for (int e = 0; e < 4; ++e) {
      unsigned short h = f2bf(v0[e]); h0e[e] = h; l0e[e] = f2bf(v0[e] - bf2f(h));
      unsigned short g = f2bf(v1[e]); h1e[e] = g; l1e[e] = f2bf(v1[e] - bf2f(g));
    }
    *(ushort4*)(ab + aoff0)        = make_ushort4(h0e[0], h0e[1], h0e[2], h0e[3]);
    *(ushort4*)(ab + 8192 + aoff0) = make_ushort4(l0e[0], l0e[1], l0e[2], l0e[3]);
    *(ushort4*)(ab + aoff1)        = make_ushort4(h1e[0], h1e[1], h1e[2], h1e[3]);
    *(ushort4*)(ab + 8192 + aoff1) = make_ushort4(l1e[0], l1e[1], l1e[2], l1e[3]);
  };

  auto compute = [&](int buf) {          // flat block: let the compiler pipeline ds_read/MFMA
    const unsigned char* bb = smem + buf * BUF_B;
    const unsigned char* ab = bb + TILE_B;
    bf16x8 ah[4], al[4];
#pragma unroll
    for (int mf = 0; mf < 4; ++mf) {
      const int m = wm * 64 + mf * 16 + l15;
      const int off = m * 64 + (jl ^ swzr(m));
      ah[mf] = *(const bf16x8*)(ab + off);
      al[mf] = *(const bf16x8*)(ab + 8192 + off);
    }
#pragma unroll
    for (int i = 0; i < 8; ++i) {
      if (i < nfc) {
        const int n = (wn + i * 4) * 16 + l15;
        const int off = n * 64 + (jl ^ swzr(n));
        const bf16x8 bh = *(const bf16x8*)(bb + off);
        const bf16x8 bl = *(const bf16x8*)(bb + 30720 + off);
#pragma unroll
        for (int mf = 0; mf < 4; ++mf) {
          acc[mf][i] = __builtin_amdgcn_mfma_f32_16x16x32_bf16(ah[mf], bh, acc[mf][i], 0, 0, 0);
          acc[mf][i] = __builtin_amdgcn_mfma_f32_16x16x32_bf16(al[mf], bh, acc[mf][i], 0, 0, 0);
          acc[mf][i] = __builtin_amdgcn_mfma_f32_16x16x32_bf16(ah[mf], bl, acc[mf][i], 0, 0, 0);
        }
      }
    }
  };

  const int ntiles = t1 - t0;
  if (ntiles >= 2) {
    f32x4 p0, p1, q0, q1;                // A-reg double pipeline: set P (even), set Q (odd)
    stageB(t0, 0);
    loadA(t0, p0, p1);
    ASM_VMCNT0();                        // drain stage(t0) + loadA(t0) before writeA/barrier
    writeA(0, p0, p1);
    loadA(t0 + 1, q0, q1);               // 2 x-loads stay in flight across the barrier
    ASM_LGKM0();
    __builtin_amdgcn_s_barrier();

    for (int t = t0; t < t1; ++t) {
      const bool doW = (t + 1 < t1);     // write A(t+1) + stage B(t+1) into freed buffer
      const bool doL = (t + 2 < t1);     // issue x-loads for t+2 (full-iteration latency cover)
      if (((t - t0) & 1) == 0) {
        if (doW) { writeA(1, q0, q1); stageB(t + 1, 1); }
        if (doL) loadA(t + 2, p0, p1);
        compute(0);
        if (doW) {
          if (doL) { ASM_VMCNT2(); } else { ASM_VMCNT0(); }   // drain stage, keep x-loads
          ASM_LGKM0();
          __builtin_amdgcn_s_barrier();
        }
      } else {
        if (doW) { writeA(0, p0, p1); stageB(t + 1, 0); }
        if (doL) loadA(t + 2, q0, q1);
        compute(1);
        if (doW) {
          if (doL) { ASM_VMCNT2(); } else { ASM_VMCNT0(); }
          ASM_LGKM0();
          __builtin_amdgcn_s_barrier();
        }
      }
    }
  } else if (ntiles == 1) {              // pathological short chunk: single-buffer path
    f32x4 r0, r1;
    stageB(t0, 0);
    loadA(t0, r0, r1);
    ASM_VMCNT0();
    writeA(0, r0, r1);
    ASM_LGKM0();
    __builtin_amdgcn_s_barrier();
    compute(0);
  }

  // epilogue: C/D frag map (m89): lane l, reg r -> row=(l>>4)*4+r, col=l&15
  float* pout = partials + ((size_t)chunk * BATCH + m0) * NPAD;
#pragma unroll
  for (int mf = 0; mf < 4; ++mf)
#pragma unroll
    for (int i = 0; i < 8; ++i) {
      if (i < nfc) {
#pragma unroll
        for (int r = 0; r < 4; ++r) {
          const int row = wm * 64 + mf * 16 + (lane >> 4) * 4 + r;
          const int col = (wn + i * 4) * 16 + l15;
          pout[(size_t)row * NPAD + col] = acc[mf][i][r];
        }
      }
    }
}

// ---------------- finish: reduce + bias + softmax x2 + outer-product store ----------------
__global__ __launch_bounds__(512) void hs_finish(
    const float* __restrict__ partials, const float* __restrict__ b0,
    const float* __restrict__ b1, float* __restrict__ out, int ksplit) {
  const int b = blockIdx.x;
  __shared__ float lg[NPAD];
  __shared__ float red[4];          // {max0, 1/sum0, max1, 1/sum1}
  const int tid = threadIdx.x;
  if (tid < NPAD) {
    float v = 0.f;
    for (int c = 0; c < ksplit; ++c)
      v += partials[((size_t)c * BATCH + b) * NPAD + tid];
    if (tid < LSZ) v += b0[tid];
    else if (tid >= HOFF && tid < HOFF + LSZ) v += b1[tid - HOFF];
    lg[tid] = v;
  }
  __syncthreads();
  const int wid = tid >> 6, lane = tid & 63;
  if (wid < 2) {                    // wave 0 -> head0, wave 1 -> head1
    const int base = wid * HOFF;
    float m = -1e30f;
    for (int i = lane; i < LSZ; i += 64) m = fmaxf(m, lg[base + i]);
#pragma unroll
    for (int s = 32; s; s >>= 1) m = fmaxf(m, __shfl_xor(m, s));
    float sum = 0.f;
    for (int i = lane; i < LSZ; i += 64) sum += __expf(lg[base + i] - m);
#pragma unroll
    for (int s = 32; s; s >>= 1) sum += __shfl_xor(sum, s);
    if (lane == 0) { red[wid * 2] = m; red[wid * 2 + 1] = 1.0f / sum; }
  }
  __syncthreads();
  if (tid < NPAD) {                 // own-index read-modify-write: no extra barrier needed
    const int h = (tid >= HOFF) ? 1 : 0;
    const int off = tid - (h ? HOFF : 0);
    float hv = 0.f;
    if (off < LSZ) hv = __expf(lg[tid] - red[2 * h]) * red[2 * h + 1];
    lg[tid] = hv;
  }
  __syncthreads();
  const size_t ob = (size_t)b * KDIM;
  for (int f = tid; f < KDIM; f += 512) {
    const int i = f / LSZ;          // compiler magic-mul
    const int j = f - i * LSZ;
    out[ob + f] = lg[i] * lg[HOFF + j];
  }
}

extern "C" void kernel_launch(void* const* d_in, const int* in_sizes, int n_in,
                              void* d_out, int out_size, void* d_ws, size_t ws_size,
                              hipStream_t stream) {
  (void)in_sizes; (void)n_in; (void)out_size;
  const float* x  = (const float*)d_in[0];
  const float* W0 = (const float*)d_in[1];
  const float* W1 = (const float*)d_in[2];
  const float* b0 = (const float*)d_in[3];
  const float* b1 = (const float*)d_in[4];
  float* out = (float*)d_out;
  unsigned char* ws = (unsigned char*)d_ws;

  const size_t WT_BYTES  = (size_t)NT * TILE_B;            // 96.5 MB
  const size_t PER_CHUNK = (size_t)BATCH * NPAD * sizeof(float);
  int ksplit = 16;
  if (ws_size > WT_BYTES) {
    const int kmax = (int)((ws_size - WT_BYTES) / PER_CHUNK);
    if (ksplit > kmax) ksplit = kmax;
  } else {
    ksplit = 1;
  }
  if (ksplit < 1) ksplit = 1;
  float* partials = (float*)(ws + WT_BYTES);
  const int tpc = (NT + ksplit - 1) / ksplit;

  hs_prep<<<dim3(NT), dim3(512), 0, stream>>>(W0, W1, ws);
  hipFuncSetAttribute((const void*)hs_gemm,
                      hipFuncAttributeMaxDynamicSharedMemorySize, LDS_TOT);
  hs_gemm<<<dim3(16 * ksplit), dim3(512), LDS_TOT, stream>>>(x, ws, partials, ksplit, tpc);
  hs_finish<<<dim3(BATCH), dim3(512), 0, stream>>>(partials, b0, b1, out, ksplit);
}

// Round 4
// 484.234 us; speedup vs baseline: 3.5042x; 3.5042x over previous
//
#include <hip/hip_runtime.h>
#include <stdint.h>
#include <math.h>

// HierarchicalSoftmax: out[b, i*225+j] = softmax(x@W0+b0)[b,i] * softmax(x@W1+b1)[b,j], f<50257
//
// Pipeline:
//  1) hs_prep : W0,W1 fp32 [K][225] -> ws: per-K-tile images of W^T [480][BK] bf16 hi/lo,
//               XOR-swizzled so GEMM can global_load_lds linearly and ds_read conflict-free.
//  2) hs_gemm : logits = x @ [W0|W1] via 3-term bf16 split (hi*hi + lo*hi + hi*lo), fp32 acc,
//               split-K partials to ws. BM=64 / 4 waves / single-buffer LDS -> 2 blocks/CU:
//               co-resident blocks run anti-phase so one block's MFMA covers the other's
//               staging drain. Per-wave register shape identical to the proven R1 kernel
//               (acc[2][15] -> AGPRs; R3's acc[4][8]+runtime-guard spilled 5.4GB to scratch).
//  3) hs_finish: reduce partials + bias, per-head softmax, fused outer-product store.

#define BATCH   2048
#define KDIM    50257
#define LSZ     225
#define HOFF    240        // head1 column offset in padded logits
#define NPAD    480        // padded N: [0,225) = head0, [240,465) = head1, rest zero
#define BK      32
#define BM      64
#define NT      1571       // ceil(50257/32)
#define TILE_B  61440      // B tile bytes: 480 rows * 64B * 2 (hi+lo)
#define A_BYTES 8192       // A tile bytes: 64 rows * 64B * 2 (hi+lo)
#define BUF_B   69632      // TILE_B + A_BYTES  (single buffer; 2 blocks/CU: 2*69632 < 160KB)

typedef __attribute__((ext_vector_type(8))) __bf16  bf16x8;
typedef __attribute__((ext_vector_type(4))) float   f32x4;

__device__ __forceinline__ unsigned short f2bf(float f) {   // RNE fp32->bf16
  unsigned int u = __float_as_uint(f);
  u += 0x7FFFu + ((u >> 16) & 1u);
  return (unsigned short)(u >> 16);
}
__device__ __forceinline__ float bf2f(unsigned short h) {
  return __uint_as_float(((unsigned int)h) << 16);
}
// XOR swizzle: flip byte-offset bits 4-5 by row bits 1-2 -> frag ds_read_b128 is 2-way (free)
__device__ __forceinline__ int swzr(int r) { return ((r >> 1) & 3) << 4; }

#define ASM_VMCNT0() asm volatile("s_waitcnt vmcnt(0)" ::: "memory")
#define ASM_LGKM0()  asm volatile("s_waitcnt lgkmcnt(0)" ::: "memory")

// ---------------- prep: build swizzled, tiled bf16 hi/lo W^T ----------------
__global__ __launch_bounds__(512) void hs_prep(const float* __restrict__ W0,
                                               const float* __restrict__ W1,
                                               unsigned char* __restrict__ wt) {
  const int kt = blockIdx.x;           // one K-tile per block
  const int k0 = kt * BK;
  unsigned char* tb = wt + (size_t)kt * TILE_B;
  for (int idx = threadIdx.x; idx < NPAD * 8; idx += 512) {
    const int n = idx >> 3, c4 = idx & 7;       // row n, 4-elem group c4
    const float* src = nullptr;
    if (n < HOFF) { if (n < LSZ) src = W0 + n; }
    else          { if (n - HOFF < LSZ) src = W1 + (n - HOFF); }
    unsigned short he[4], le[4];
#pragma unroll
    for (int e = 0; e < 4; ++e) {
      const int k = k0 + c4 * 4 + e;
      float v = (src != nullptr && k < KDIM) ? src[(size_t)k * LSZ] : 0.0f;
      const unsigned short h = f2bf(v);
      he[e] = h;
      le[e] = f2bf(v - bf2f(h));
    }
    const int jp = (c4 * 8) ^ swzr(n);
    *(ushort4*)(tb + n * 64 + jp)         = make_ushort4(he[0], he[1], he[2], he[3]);
    *(ushort4*)(tb + 30720 + n * 64 + jp) = make_ushort4(le[0], le[1], le[2], le[3]);
  }
}

// ---------------- GEMM: 64x480 tile, BK=32, 4 waves (2m x 2n), split-K ----------------
__global__ __launch_bounds__(256, 2) void hs_gemm(
    const float* __restrict__ x, const unsigned char* __restrict__ wt,
    float* __restrict__ partials, int ksplit, int tpc) {
  extern __shared__ __align__(16) unsigned char smem[];
  const int bid   = blockIdx.x;
  const int chunk = bid % ksplit;            // same-chunk blocks cluster on XCDs (wt L2 reuse)
  const int mtile = bid / ksplit;
  const int t0 = chunk * tpc;
  int t1 = t0 + tpc; if (t1 > NT) t1 = NT;
  const int m0 = mtile * BM;
  const int tid = threadIdx.x;
  const int lane = tid & 63, wid = tid >> 6;
  const int wm = wid >> 1, wn = wid & 1;     // wave tile: 32 rows x 240 cols (as R1)
  const int jl  = (lane >> 4) * 16;          // frag k-offset bytes
  const int l15 = lane & 15;

  // A staging geometry: thread covers rows arow0 and arow0+32, 4 k-elems each
  const int arow0 = tid >> 3, c4 = tid & 7;
  const int arow1 = arow0 + 32;
  const float* xr0 = x + (size_t)(m0 + arow0) * KDIM + c4 * 4;
  const float* xr1 = xr0 + (size_t)32 * KDIM;
  const int aoff0 = arow0 * 64 + ((c4 * 8) ^ swzr(arow0));
  const int aoff1 = arow1 * 64 + ((c4 * 8) ^ swzr(arow1));

  f32x4 acc[2][15];
#pragma unroll
  for (int mf = 0; mf < 2; ++mf)
#pragma unroll
    for (int nf = 0; nf < 15; ++nf)
      acc[mf][nf] = f32x4{0.f, 0.f, 0.f, 0.f};

  auto stageB = [&](int kt) {            // 60 x 1KB wave-chunks, pre-swizzled in ws
    const unsigned char* src = wt + (size_t)kt * TILE_B + lane * 16;
#pragma unroll
    for (int c = 0; c < 15; ++c) {
      const int cc = wid + c * 4;
      __builtin_amdgcn_global_load_lds(
          (const __attribute__((address_space(1))) unsigned int*)(src + cc * 1024),
          (__attribute__((address_space(3))) unsigned int*)(smem + cc * 1024),
          16, 0, 0);
    }
  };

  auto loadA = [&](int kt, f32x4& v0, f32x4& v1) {
    const int kb = kt * BK + c4 * 4;
    const float* p0 = xr0 + (size_t)kt * BK;
    const float* p1 = xr1 + (size_t)kt * BK;
    if (kb + 4 <= KDIM) {
      __builtin_memcpy(&v0, p0, 16);
      __builtin_memcpy(&v1, p1, 16);
    } else {
#pragma unroll
      for (int e = 0; e < 4; ++e) {
        v0[e] = (kb + e < KDIM) ? p0[e] : 0.f;
        v1[e] = (kb + e < KDIM) ? p1[e] : 0.f;
      }
    }
  };

  auto writeA = [&](const f32x4& v0, const f32x4& v1) {
    unsigned char* ab = smem + TILE_B;
    unsigned short h0e[4], l0e[4], h1e[4], l1e[4];
#pragma unroll
    for (int e = 0; e < 4; ++e) {
      unsigned short h = f2bf(v0[e]); h0e[e] = h; l0e[e] = f2bf(v0[e] - bf2f(h));
      unsigned short g = f2bf(v1[e]); h1e[e] = g; l1e[e] = f2bf(v1[e] - bf2f(g));
    }
    *(ushort4*)(ab + aoff0)        = make_ushort4(h0e[0], h0e[1], h0e[2], h0e[3]);
    *(ushort4*)(ab + 4096 + aoff0) = make_ushort4(l0e[0], l0e[1], l0e[2], l0e[3]);
    *(ushort4*)(ab + aoff1)        = make_ushort4(h1e[0], h1e[1], h1e[2], h1e[3]);
    *(ushort4*)(ab + 4096 + aoff1) = make_ushort4(l1e[0], l1e[1], l1e[2], l1e[3]);
  };

  auto compute = [&]() {                 // flat block: compiler pipelines ds_read/MFMA
    const unsigned char* bb = smem;
    const unsigned char* ab = smem + TILE_B;
    bf16x8 ah[2], al[2];
#pragma unroll
    for (int mf = 0; mf < 2; ++mf) {
      const int m = wm * 32 + mf * 16 + l15;
      const int off = m * 64 + (jl ^ swzr(m));
      ah[mf] = *(const bf16x8*)(ab + off);
      al[mf] = *(const bf16x8*)(ab + 4096 + off);
    }
#pragma unroll
    for (int nf = 0; nf < 15; ++nf) {
      const int n = wn * 240 + nf * 16 + l15;
      const int off = n * 64 + (jl ^ swzr(n));
      const bf16x8 bh = *(const bf16x8*)(bb + off);
      const bf16x8 bl = *(const bf16x8*)(bb + 30720 + off);
#pragma unroll
      for (int mf = 0; mf < 2; ++mf) {
        acc[mf][nf] = __builtin_amdgcn_mfma_f32_16x16x32_bf16(ah[mf], bh, acc[mf][nf], 0, 0, 0);
        acc[mf][nf] = __builtin_amdgcn_mfma_f32_16x16x32_bf16(al[mf], bh, acc[mf][nf], 0, 0, 0);
        acc[mf][nf] = __builtin_amdgcn_mfma_f32_16x16x32_bf16(ah[mf], bl, acc[mf][nf], 0, 0, 0);
      }
    }
  };

  if (t0 < t1) {
    f32x4 r0, r1;
    stageB(t0);
    loadA(t0, r0, r1);
    ASM_VMCNT0();                        // stage(t0) + loadA(t0) complete
    writeA(r0, r1);
    ASM_LGKM0();
    __builtin_amdgcn_s_barrier();

    for (int t = t0; t < t1; ++t) {
      const bool more = (t + 1 < t1);
      if (more) loadA(t + 1, r0, r1);    // x-loads in flight during compute (reg-only, WAR-safe)
      compute();
      __builtin_amdgcn_s_barrier();      // all waves done reading LDS tile t
      if (more) {
        stageB(t + 1);                   // refill same buffer; other block's compute covers this
        ASM_VMCNT0();
        writeA(r0, r1);
        ASM_LGKM0();
        __builtin_amdgcn_s_barrier();
      }
    }
  }

  // epilogue: C/D frag map (m89): lane l, reg r -> row=(l>>4)*4+r, col=l&15
  float* pout = partials + ((size_t)chunk * BATCH + m0) * NPAD;
#pragma unroll
  for (int mf = 0; mf < 2; ++mf)
#pragma unroll
    for (int nf = 0; nf < 15; ++nf)
#pragma unroll
      for (int r = 0; r < 4; ++r) {
        const int row = wm * 32 + mf * 16 + (lane >> 4) * 4 + r;
        const int col = wn * 240 + nf * 16 + l15;
        pout[(size_t)row * NPAD + col] = acc[mf][nf][r];
      }
}

// ---------------- finish: reduce + bias + softmax x2 + outer-product store ----------------
__global__ __launch_bounds__(512) void hs_finish(
    const float* __restrict__ partials, const float* __restrict__ b0,
    const float* __restrict__ b1, float* __restrict__ out, int ksplit) {
  const int b = blockIdx.x;
  __shared__ float lg[NPAD];
  __shared__ float red[4];          // {max0, 1/sum0, max1, 1/sum1}
  const int tid = threadIdx.x;
  if (tid < NPAD) {
    float v = 0.f;
    for (int c = 0; c < ksplit; ++c)
      v += partials[((size_t)c * BATCH + b) * NPAD + tid];
    if (tid < LSZ) v += b0[tid];
    else if (tid >= HOFF && tid < HOFF + LSZ) v += b1[tid - HOFF];
    lg[tid] = v;
  }
  __syncthreads();
  const int wid = tid >> 6, lane = tid & 63;
  if (wid < 2) {                    // wave 0 -> head0, wave 1 -> head1
    const int base = wid * HOFF;
    float m = -1e30f;
    for (int i = lane; i < LSZ; i += 64) m = fmaxf(m, lg[base + i]);
#pragma unroll
    for (int s = 32; s; s >>= 1) m = fmaxf(m, __shfl_xor(m, s));
    float sum = 0.f;
    for (int i = lane; i < LSZ; i += 64) sum += __expf(lg[base + i] - m);
#pragma unroll
    for (int s = 32; s; s >>= 1) sum += __shfl_xor(sum, s);
    if (lane == 0) { red[wid * 2] = m; red[wid * 2 + 1] = 1.0f / sum; }
  }
  __syncthreads();
  if (tid < NPAD) {                 // own-index read-modify-write: no extra barrier needed
    const int h = (tid >= HOFF) ? 1 : 0;
    const int off = tid - (h ? HOFF : 0);
    float hv = 0.f;
    if (off < LSZ) hv = __expf(lg[tid] - red[2 * h]) * red[2 * h + 1];
    lg[tid] = hv;
  }
  __syncthreads();
  const size_t ob = (size_t)b * KDIM;
  for (int f = tid; f < KDIM; f += 512) {
    const int i = f / LSZ;          // compiler magic-mul
    const int j = f - i * LSZ;
    out[ob + f] = lg[i] * lg[HOFF + j];
  }
}

extern "C" void kernel_launch(void* const* d_in, const int* in_sizes, int n_in,
                              void* d_out, int out_size, void* d_ws, size_t ws_size,
                              hipStream_t stream) {
  (void)in_sizes; (void)n_in; (void)out_size;
  const float* x  = (const float*)d_in[0];
  const float* W0 = (const float*)d_in[1];
  const float* W1 = (const float*)d_in[2];
  const float* b0 = (const float*)d_in[3];
  const float* b1 = (const float*)d_in[4];
  float* out = (float*)d_out;
  unsigned char* ws = (unsigned char*)d_ws;

  const size_t WT_BYTES  = (size_t)NT * TILE_B;            // 96.5 MB
  const size_t PER_CHUNK = (size_t)BATCH * NPAD * sizeof(float);
  int ksplit = 16;
  if (ws_size > WT_BYTES) {
    const int kmax = (int)((ws_size - WT_BYTES) / PER_CHUNK);
    if (ksplit > kmax) ksplit = kmax;
  } else {
    ksplit = 1;
  }
  if (ksplit < 1) ksplit = 1;
  float* partials = (float*)(ws + WT_BYTES);
  const int tpc = (NT + ksplit - 1) / ksplit;

  hs_prep<<<dim3(NT), dim3(512), 0, stream>>>(W0, W1, ws);
  hipFuncSetAttribute((const void*)hs_gemm,
                      hipFuncAttributeMaxDynamicSharedMemorySize, BUF_B);
  hs_gemm<<<dim3(32 * ksplit), dim3(256), BUF_B, stream>>>(x, ws, partials, ksplit, tpc);
  hs_finish<<<dim3(BATCH), dim3(512), 0, stream>>>(partials, b0, b1, out, ksplit);
}

// Round 5
// 349.922 us; speedup vs baseline: 4.8493x; 1.3838x over previous
//
#include <hip/hip_runtime.h>
#include <stdint.h>
#include <math.h>

// HierarchicalSoftmax: out[b, i*225+j] = softmax(x@W0+b0)[b,i] * softmax(x@W1+b1)[b,j], f<50257
//
// Pipeline (R5: fp16 2-term replaces bf16 3-term; structure = proven R1 loop):
//  1) hs_prep : W0,W1 fp32 [K][225] -> ws: per-K-tile images of W^T [480][BK] fp16 (x1024),
//               XOR-swizzled so GEMM can global_load_lds linearly and ds_read conflict-free.
//  2) hs_gemm : logits*1024 = x @ [W0|W1]*1024 via x = xh + xl (fp16 pair, exact to 2^-22),
//               W single fp16: 2 MFMA terms (xh*W + xl*W), fp32 acc, split-K partials to ws.
//               W rounding (std 2.8e-4 rel) -> logit err ~4e-4 std; output absmax ~3e-4 << 1.47e-3.
//  3) hs_finish: reduce partials * 2^-10 + bias, per-head softmax, fused outer-product store.

#define BATCH   2048
#define KDIM    50257
#define LSZ     225
#define HOFF    240        // head1 column offset in padded logits
#define NPAD    480        // padded N: [0,225) = head0, [240,465) = head1, rest zero
#define BK      32
#define BM      128
#define NT      1571       // ceil(50257/32)
#define TILE_B  30720      // B tile bytes: 480 rows * 64B (fp16, single image)
#define A_BYTES 16384      // A tile bytes: 128 rows * 64B * 2 (xh + xl)
#define BUF_B   47104      // TILE_B + A_BYTES
#define LDS_TOT 94208      // 2 * BUF_B (double buffer)
#define WSCALE  1024.0f    // W pre-scale: keeps fp16 weights out of denormal range

typedef __attribute__((ext_vector_type(8))) _Float16 f16x8;
typedef __attribute__((ext_vector_type(4))) float    f32x4;

__device__ __forceinline__ unsigned short f2h(float f) {    // fp32 -> fp16 bits (RNE)
  return __builtin_bit_cast(unsigned short, (_Float16)f);
}
// XOR swizzle: flip byte-offset bits 4-5 by row bits 1-2 -> frag ds_read_b128 is 2-way (free)
__device__ __forceinline__ int swzr(int r) { return ((r >> 1) & 3) << 4; }

// ---------------- prep: build swizzled, tiled fp16 W^T (scaled x1024) ----------------
__global__ __launch_bounds__(512) void hs_prep(const float* __restrict__ W0,
                                               const float* __restrict__ W1,
                                               unsigned char* __restrict__ wt) {
  const int kt = blockIdx.x;           // one K-tile per block
  const int k0 = kt * BK;
  unsigned char* tb = wt + (size_t)kt * TILE_B;
  for (int idx = threadIdx.x; idx < NPAD * 8; idx += 512) {
    const int n = idx >> 3, c4 = idx & 7;       // row n, 4-elem group c4
    const float* src = nullptr;
    if (n < HOFF) { if (n < LSZ) src = W0 + n; }
    else          { if (n - HOFF < LSZ) src = W1 + (n - HOFF); }
    unsigned short he[4];
#pragma unroll
    for (int e = 0; e < 4; ++e) {
      const int k = k0 + c4 * 4 + e;
      float v = (src != nullptr && k < KDIM) ? src[(size_t)k * LSZ] * WSCALE : 0.0f;
      he[e] = f2h(v);
    }
    const int jp = (c4 * 8) ^ swzr(n);
    *(ushort4*)(tb + n * 64 + jp) = make_ushort4(he[0], he[1], he[2], he[3]);
  }
}

// ---------------- GEMM: 128x480 tile, BK=32, 8 waves (4m x 2n), split-K ----------------
__global__ __launch_bounds__(512, 2) void hs_gemm(
    const float* __restrict__ x, const unsigned char* __restrict__ wt,
    float* __restrict__ partials, int ksplit, int tpc) {
  extern __shared__ __align__(16) unsigned char smem[];
  const int bid   = blockIdx.x;
  const int chunk = bid % ksplit;            // same-chunk blocks share XCD (bid%8 == chunk%8)
  const int mtile = bid / ksplit;
  const int t0 = chunk * tpc;
  int t1 = t0 + tpc; if (t1 > NT) t1 = NT;
  const int m0 = mtile * BM;
  const int tid = threadIdx.x;
  const int lane = tid & 63, wid = tid >> 6;
  const int wm = wid >> 1, wn = wid & 1;     // wave tile: 32 rows x 240 cols
  const int jl  = (lane >> 4) * 16;          // frag k-offset bytes
  const int l15 = lane & 15;

  // A staging geometry: thread covers rows arow0 and arow0+64, 4 k-elems each
  const int arow0 = tid >> 3, c4 = tid & 7;
  const int arow1 = arow0 + 64;
  const float* xr0 = x + (size_t)(m0 + arow0) * KDIM + c4 * 4;
  const float* xr1 = xr0 + (size_t)64 * KDIM;
  const int aoff0 = arow0 * 64 + ((c4 * 8) ^ swzr(arow0));
  const int aoff1 = arow1 * 64 + ((c4 * 8) ^ swzr(arow1));

  f32x4 acc[2][15];
#pragma unroll
  for (int mf = 0; mf < 2; ++mf)
#pragma unroll
    for (int nf = 0; nf < 15; ++nf)
      acc[mf][nf] = f32x4{0.f, 0.f, 0.f, 0.f};

  auto stageB = [&](int kt, int buf) {   // 30 x 1KB wave-chunks, pre-swizzled in ws
    const unsigned char* src = wt + (size_t)kt * TILE_B + lane * 16;
    unsigned char* dstb = smem + buf * BUF_B;
#pragma unroll
    for (int c = 0; c < 4; ++c) {
      const int cc = wid + c * 8;
      if (cc < 30) {
        __builtin_amdgcn_global_load_lds(
            (const __attribute__((address_space(1))) unsigned int*)(src + cc * 1024),
            (__attribute__((address_space(3))) unsigned int*)(dstb + cc * 1024),
            16, 0, 0);
      }
    }
  };

  auto loadA = [&](int kt, f32x4& v0, f32x4& v1) {
    const int kb = kt * BK + c4 * 4;
    const float* p0 = xr0 + (size_t)kt * BK;
    const float* p1 = xr1 + (size_t)kt * BK;
    if (kb + 4 <= KDIM) {
      __builtin_memcpy(&v0, p0, 16);
      __builtin_memcpy(&v1, p1, 16);
    } else {
#pragma unroll
      for (int e = 0; e < 4; ++e) {
        v0[e] = (kb + e < KDIM) ? p0[e] : 0.f;
        v1[e] = (kb + e < KDIM) ? p1[e] : 0.f;
      }
    }
  };

  auto writeA = [&](int buf, const f32x4& v0, const f32x4& v1) {
    unsigned char* ab = smem + buf * BUF_B + TILE_B;
    unsigned short h0e[4], l0e[4], h1e[4], l1e[4];
#pragma unroll
    for (int e = 0; e < 4; ++e) {
      const _Float16 h = (_Float16)v0[e];
      h0e[e] = __builtin_bit_cast(unsigned short, h);
      l0e[e] = f2h(v0[e] - (float)h);
      const _Float16 g = (_Float16)v1[e];
      h1e[e] = __builtin_bit_cast(unsigned short, g);
      l1e[e] = f2h(v1[e] - (float)g);
    }
    *(ushort4*)(ab + aoff0)        = make_ushort4(h0e[0], h0e[1], h0e[2], h0e[3]);
    *(ushort4*)(ab + 8192 + aoff0) = make_ushort4(l0e[0], l0e[1], l0e[2], l0e[3]);
    *(ushort4*)(ab + aoff1)        = make_ushort4(h1e[0], h1e[1], h1e[2], h1e[3]);
    *(ushort4*)(ab + 8192 + aoff1) = make_ushort4(l1e[0], l1e[1], l1e[2], l1e[3]);
  };

  auto compute = [&](int buf) {          // flat block: compiler pipelines ds_read/MFMA
    const unsigned char* bb = smem + buf * BUF_B;
    const unsigned char* ab = bb + TILE_B;
    f16x8 ah[2], al[2];
#pragma unroll
    for (int mf = 0; mf < 2; ++mf) {
      const int m = wm * 32 + mf * 16 + l15;
      const int off = m * 64 + (jl ^ swzr(m));
      ah[mf] = *(const f16x8*)(ab + off);
      al[mf] = *(const f16x8*)(ab + 8192 + off);
    }
#pragma unroll
    for (int nf = 0; nf < 15; ++nf) {
      const int n = wn * 240 + nf * 16 + l15;
      const int off = n * 64 + (jl ^ swzr(n));
      const f16x8 bw = *(const f16x8*)(bb + off);
#pragma unroll
      for (int mf = 0; mf < 2; ++mf) {
        acc[mf][nf] = __builtin_amdgcn_mfma_f32_16x16x32_f16(ah[mf], bw, acc[mf][nf], 0, 0, 0);
        acc[mf][nf] = __builtin_amdgcn_mfma_f32_16x16x32_f16(al[mf], bw, acc[mf][nf], 0, 0, 0);
      }
    }
  };

  if (t0 < t1) {
    f32x4 v0, v1;
    stageB(t0, 0);
    loadA(t0, v0, v1);
    writeA(0, v0, v1);
    __syncthreads();
    int buf = 0;
    for (int t = t0; t < t1; ++t) {
      const bool more = (t + 1 < t1);
      if (more) {                 // prefetch next tile before compute (2-phase)
        stageB(t + 1, buf ^ 1);
        loadA(t + 1, v0, v1);
      }
      compute(buf);
      if (more) writeA(buf ^ 1, v0, v1);
      __syncthreads();
      buf ^= 1;
    }
  }

  // epilogue: C/D frag map (m89): lane l, reg r -> row=(l>>4)*4+r, col=l&15
  float* pout = partials + ((size_t)chunk * BATCH + m0) * NPAD;
#pragma unroll
  for (int mf = 0; mf < 2; ++mf)
#pragma unroll
    for (int nf = 0; nf < 15; ++nf)
#pragma unroll
      for (int r = 0; r < 4; ++r) {
        const int row = wm * 32 + mf * 16 + (lane >> 4) * 4 + r;
        const int col = wn * 240 + nf * 16 + l15;
        pout[(size_t)row * NPAD + col] = acc[mf][nf][r];
      }
}

// ---------------- finish: reduce + bias + softmax x2 + outer-product store ----------------
__global__ __launch_bounds__(512) void hs_finish(
    const float* __restrict__ partials, const float* __restrict__ b0,
    const float* __restrict__ b1, float* __restrict__ out, int ksplit) {
  const int b = blockIdx.x;
  __shared__ float lg[NPAD];
  __shared__ float red[4];          // {max0, 1/sum0, max1, 1/sum1}
  const int tid = threadIdx.x;
  if (tid < NPAD) {
    float v = 0.f;
    for (int c = 0; c < ksplit; ++c)
      v += partials[((size_t)c * BATCH + b) * NPAD + tid];
    v *= (1.0f / WSCALE);           // undo W pre-scale
    if (tid < LSZ) v += b0[tid];
    else if (tid >= HOFF && tid < HOFF + LSZ) v += b1[tid - HOFF];
    lg[tid] = v;
  }
  __syncthreads();
  const int wid = tid >> 6, lane = tid & 63;
  if (wid < 2) {                    // wave 0 -> head0, wave 1 -> head1
    const int base = wid * HOFF;
    float m = -1e30f;
    for (int i = lane; i < LSZ; i += 64) m = fmaxf(m, lg[base + i]);
#pragma unroll
    for (int s = 32; s; s >>= 1) m = fmaxf(m, __shfl_xor(m, s));
    float sum = 0.f;
    for (int i = lane; i < LSZ; i += 64) sum += __expf(lg[base + i] - m);
#pragma unroll
    for (int s = 32; s; s >>= 1) sum += __shfl_xor(sum, s);
    if (lane == 0) { red[wid * 2] = m; red[wid * 2 + 1] = 1.0f / sum; }
  }
  __syncthreads();
  if (tid < NPAD) {                 // own-index read-modify-write: no extra barrier needed
    const int h = (tid >= HOFF) ? 1 : 0;
    const int off = tid - (h ? HOFF : 0);
    float hv = 0.f;
    if (off < LSZ) hv = __expf(lg[tid] - red[2 * h]) * red[2 * h + 1];
    lg[tid] = hv;
  }
  __syncthreads();
  const size_t ob = (size_t)b * KDIM;
  for (int f = tid; f < KDIM; f += 512) {
    const int i = f / LSZ;          // compiler magic-mul
    const int j = f - i * LSZ;
    out[ob + f] = lg[i] * lg[HOFF + j];
  }
}

extern "C" void kernel_launch(void* const* d_in, const int* in_sizes, int n_in,
                              void* d_out, int out_size, void* d_ws, size_t ws_size,
                              hipStream_t stream) {
  (void)in_sizes; (void)n_in; (void)out_size;
  const float* x  = (const float*)d_in[0];
  const float* W0 = (const float*)d_in[1];
  const float* W1 = (const float*)d_in[2];
  const float* b0 = (const float*)d_in[3];
  const float* b1 = (const float*)d_in[4];
  float* out = (float*)d_out;
  unsigned char* ws = (unsigned char*)d_ws;

  const size_t WT_BYTES  = (size_t)NT * TILE_B;            // 48.3 MB
  const size_t PER_CHUNK = (size_t)BATCH * NPAD * sizeof(float);
  int ksplit = 16;
  if (ws_size > WT_BYTES) {
    const int kmax = (int)((ws_size - WT_BYTES) / PER_CHUNK);
    if (ksplit > kmax) ksplit = kmax;
  } else {
    ksplit = 1;
  }
  if (ksplit < 1) ksplit = 1;
  float* partials = (float*)(ws + WT_BYTES);
  const int tpc = (NT + ksplit - 1) / ksplit;

  hs_prep<<<dim3(NT), dim3(512), 0, stream>>>(W0, W1, ws);
  hipFuncSetAttribute((const void*)hs_gemm,
                      hipFuncAttributeMaxDynamicSharedMemorySize, LDS_TOT);
  hs_gemm<<<dim3(16 * ksplit), dim3(512), LDS_TOT, stream>>>(x, ws, partials, ksplit, tpc);
  hs_finish<<<dim3(BATCH), dim3(512), 0, stream>>>(partials, b0, b1, out, ksplit);
}